// Round 1
// 152.949 us; speedup vs baseline: 1.0219x; 1.0219x over previous
//
#include <hip/hip_runtime.h>

#define NU 60082
#define NST 14695
#define D 128
#define B 8
#define K 32
#define NBLK ((NU + 63) / 64)   // 939 blocks, 64 output rows each

// workspace layout (float indices)
#define WS_V    0      // 128: proj_w @ w_st
#define WS_C    128    // 1:   proj_b . w_st
#define WS_UC   136    // 8:   user_mem[b] . w_u + b_u + b_st
#define WS_NOW  192    // 256: slot t=(b*32+k): alpha[n] * (station_embedding[n] . w_st)
#define WS_HIS  448    // 256: slot t: alpha[n] * (MLP(rfe[n]) . w_st)

// ---------------------------------------------------------------------------
// k_pre: all batch-invariant scalars/vectors, computed ONCE (was recomputed in
// every one of 939 blocks / in straggler blocks). 130 blocks x 256.
//   block 0      : v[128], c
//   block 1      : uc[8]
//   blocks 2..65 : 256 now-slot values, one wave each
//   blocks 66..129: 256 his-slot values (full MLP), one wave each
// ---------------------------------------------------------------------------
__global__ __launch_bounds__(256) void k_pre(
    const float* __restrict__ user_embedding,
    const float* __restrict__ station_embedding,
    const float* __restrict__ raw_field_embed,
    const int* __restrict__ his_nodes,
    const int* __restrict__ now_nodes,
    const int* __restrict__ user_id,
    const float* __restrict__ user_emb_table,
    const float* __restrict__ proj_w,
    const float* __restrict__ proj_b,
    const float* __restrict__ theta,
    const float* __restrict__ alpha,
    const float* __restrict__ w_his1,
    const float* __restrict__ b_his1,
    const float* __restrict__ w_his2,
    const float* __restrict__ b_his2,
    const float* __restrict__ w_st,
    const float* __restrict__ b_st,
    const float* __restrict__ w_u,
    const float* __restrict__ b_u,
    float* __restrict__ ws)
{
    __shared__ float s_wst[128];
    const int t  = threadIdx.x;
    const int bb = blockIdx.x;

    if (t < 32) ((float4*)s_wst)[t] = ((const float4*)w_st)[t];
    __syncthreads();

    if (bb == 0) {
        // v = proj_w @ w_st (one row-dot per thread), c = proj_b . w_st
        if (t < 128) {
            float acc = 0.f;
            const float4* pr = (const float4*)(proj_w + t * D);
            #pragma unroll 8
            for (int j = 0; j < 32; ++j) {
                float4 x = pr[j];
                float4 wv = ((float4*)s_wst)[j];
                acc += x.x * wv.x + x.y * wv.y + x.z * wv.z + x.w * wv.w;
            }
            ws[WS_V + t] = acc;
        } else if (t < 160) {
            int l = t - 128;
            float4 x = ((const float4*)proj_b)[l];
            float4 wv = ((float4*)s_wst)[l];
            float p = x.x * wv.x + x.y * wv.y + x.z * wv.z + x.w * wv.w;
            #pragma unroll
            for (int off = 16; off >= 1; off >>= 1) p += __shfl_down(p, off, 32);
            if (l == 0) ws[WS_C] = p;
        }
    } else if (bb == 1) {
        // uc[b] = user_mem[b] . w_u + b_u + b_st   (32 threads per batch row)
        int u = t >> 5, l = t & 31;
        int uid = user_id[u];
        float th = theta[uid];
        float4 ue = ((const float4*)(user_embedding + u * D))[l];
        float4 ut = ((const float4*)(user_emb_table + (size_t)uid * D))[l];
        float4 wu = ((const float4*)w_u)[l];
        float p = ((1.f - th) * ue.x + th * ut.x) * wu.x
                + ((1.f - th) * ue.y + th * ut.y) * wu.y
                + ((1.f - th) * ue.z + th * ut.z) * wu.z
                + ((1.f - th) * ue.w + th * ut.w) * wu.w;
        #pragma unroll
        for (int off = 16; off >= 1; off >>= 1) p += __shfl_down(p, off, 32);
        if (l == 0) ws[WS_UC + u] = p + b_u[0] + b_st[0];
    } else if (bb < 66) {
        // now slot: alpha[n] * (station_embedding[n] . w_st), one wave/slot
        int w = t >> 6, lane = t & 63;
        int slot = (bb - 2) * 4 + w;
        int n = now_nodes[slot];
        const float* se = station_embedding + (size_t)n * D;
        float p = se[lane] * s_wst[lane] + se[64 + lane] * s_wst[64 + lane];
        #pragma unroll
        for (int off = 32; off >= 1; off >>= 1) p += __shfl_down(p, off, 64);
        if (lane == 0) ws[WS_NOW + slot] = alpha[n] * p;
    } else {
        // his slot: alpha[n] * (MLP(rfe[n]) . w_st), one wave/slot; lane = hidden unit
        int w = t >> 6, h = t & 63;
        int slot = (bb - 66) * 4 + w;
        int n = his_nodes[slot];
        // v2[h] = w_his2[h,:] . w_st
        float v2h = 0.f;
        const float4* wr = (const float4*)(w_his2 + h * D);
        #pragma unroll 8
        for (int j = 0; j < 32; ++j) {
            float4 x = wr[j];
            float4 wv = ((float4*)s_wst)[j];
            v2h += x.x * wv.x + x.y * wv.y + x.z * wv.z + x.w * wv.w;
        }
        // h1[h] = b_his1[h] + rfe[n] . w_his1[:,h]
        const float4* rf = (const float4*)(raw_field_embed + (size_t)n * D);
        float h1 = b_his1[h];
        #pragma unroll 8
        for (int j = 0; j < 32; ++j) {
            float4 r = rf[j];   // broadcast load
            h1 += r.x * w_his1[(4 * j + 0) * 64 + h]
                + r.y * w_his1[(4 * j + 1) * 64 + h]
                + r.z * w_his1[(4 * j + 2) * 64 + h]
                + r.w * w_his1[(4 * j + 3) * 64 + h];
        }
        float ha = h1 > 0.f ? h1 : 0.01f * h1;   // jax leaky_relu default
        // fold c2 = b_his2 . w_st into the same wave reduction
        float p = ha * v2h + b_his2[h] * s_wst[h] + b_his2[64 + h] * s_wst[64 + h];
        #pragma unroll
        for (int off = 32; off >= 1; off >>= 1) p += __shfl_down(p, off, 64);
        if (h == 0) ws[WS_HIS + slot] = alpha[n] * p;
    }
}

// ---------------------------------------------------------------------------
// k_main: block sb owns rows [sb*64, sb*64+64) for all 8 batch rows. Pure
// streaming: read v/uc/c + 512 slot values from L2, stream 64 station rows,
// accumulate slot hits into s_add via LDS atomics (exact JAX duplicate-add
// semantics), write every out element exactly once. 3 barriers, no per-block
// matrix recompute, no straggler MLP work.
// ---------------------------------------------------------------------------
__global__ __launch_bounds__(256) void k_main(
    const float* __restrict__ station_emb_table,
    const int* __restrict__ his_nodes,
    const int* __restrict__ now_nodes,
    const float* __restrict__ alpha,
    const float* __restrict__ ws,
    float* __restrict__ out)
{
    __shared__ float s_v[128];
    __shared__ float s_tile[64];
    __shared__ float s_uc[8];
    __shared__ float s_c;
    __shared__ float s_add[8 * 64];
    __shared__ unsigned char s_flag[8 * 64];

    const int t  = threadIdx.x;
    const int sb = blockIdx.x;
    const int row0 = sb * 64;
    const int w    = t >> 6;
    const int lane = t & 63;
    const int half = lane >> 5;
    const int l32  = lane & 31;

    // ---- issue all small L2 loads up front (drain at barrier #1) ----
    const int n0 = now_nodes[t];
    const int n1 = his_nodes[t];
    const float wn = ws[WS_NOW + t];
    const float wh = ws[WS_HIS + t];
    float4 vv4 = make_float4(0.f, 0.f, 0.f, 0.f);
    float ucv = 0.f, cv = 0.f;
    if (t < 32) vv4 = ((const float4*)(ws + WS_V))[t];
    if (t < 8)  ucv = ws[WS_UC + t];
    if (t == 8) cv  = ws[WS_C];

    // ---- zero accumulators / flags; park v,uc,c in LDS ----
    if (t < 128) {
        ((float4*)s_add)[t] = make_float4(0.f, 0.f, 0.f, 0.f);
        ((int*)s_flag)[t] = 0;
    }
    if (t < 32) ((float4*)s_v)[t] = vv4;
    if (t < 8)  s_uc[t] = ucv;
    if (t == 8) s_c = cv;

    // ---- issue the 8 station-row loads (the only HBM stream) ----
    float4 xr[8];
    #pragma unroll
    for (int i = 0; i < 8; ++i) {
        int r = i * 8 + w * 2 + half;
        int row = row0 + r;
        if (row < NU)
            xr[i] = ((const float4*)(station_emb_table + (size_t)row * D))[l32];
        else
            xr[i] = make_float4(0.f, 0.f, 0.f, 0.f);
    }
    __syncthreads();   // #1: zeros + s_v visible; all loads drained

    // ---- slot scatter: pure LDS ops (values precomputed by k_pre) ----
    {
        const int b = t >> 5;   // now/his are [B][K] row-major, t = b*32+k
        if ((n0 >> 6) == sb) {
            int idx = b * 64 + (n0 & 63);
            s_flag[idx] = 1;
            atomicAdd(&s_add[idx], wn);
        }
        if ((n1 >> 6) == sb) {
            int idx = b * 64 + (n1 & 63);
            s_flag[idx] = 1;
            atomicAdd(&s_add[idx], wh);
        }
    }
    __syncthreads();   // #2: cheap (LDS only outstanding)

    // ---- dot products: s[n] = st_row . v + c ----
    {
        const float4 vv = ((const float4*)s_v)[l32];
        const float  c  = s_c;
        #pragma unroll
        for (int i = 0; i < 8; ++i) {
            int r = i * 8 + w * 2 + half;
            float acc = xr[i].x * vv.x + xr[i].y * vv.y + xr[i].z * vv.z + xr[i].w * vv.w;
            #pragma unroll
            for (int off = 16; off >= 1; off >>= 1) acc += __shfl_down(acc, off, 32);
            if (l32 == 0) s_tile[r] = acc + c;
        }
    }
    __syncthreads();   // #3

    // ---- single write pass: every (b,row) written exactly once ----
    {
        const int nl  = t & 63;
        const int b0  = t >> 6;        // handles planes b0 and b0+4
        const int row = row0 + nl;
        if (row < NU) {
            const float sv = s_tile[nl];
            const int f0 = s_flag[b0 * 64 + nl];
            const int f1 = s_flag[(b0 + 4) * 64 + nl];
            float a = 0.f;
            if (f0 | f1) a = alpha[row];   // rare, L2
            const float o0 = f0 ? sv * (1.f - a) + s_add[b0 * 64 + nl]       : sv;
            const float o1 = f1 ? sv * (1.f - a) + s_add[(b0 + 4) * 64 + nl] : sv;
            out[(size_t)b0 * NU + row]       = o0 + s_uc[b0];
            out[(size_t)(b0 + 4) * NU + row] = o1 + s_uc[b0 + 4];
        }
    }
}

extern "C" void kernel_launch(void* const* d_in, const int* in_sizes, int n_in,
                              void* d_out, int out_size, void* d_ws, size_t ws_size,
                              hipStream_t stream) {
    const float* user_embedding    = (const float*)d_in[0];
    const float* station_embedding = (const float*)d_in[1];
    const float* raw_field_embed   = (const float*)d_in[2];
    const int*   his_nodes         = (const int*)d_in[3];
    const int*   now_nodes         = (const int*)d_in[4];
    const int*   user_id           = (const int*)d_in[5];
    const float* user_emb_table    = (const float*)d_in[6];
    const float* station_emb_table = (const float*)d_in[7];
    const float* proj_w            = (const float*)d_in[8];
    const float* proj_b            = (const float*)d_in[9];
    const float* theta             = (const float*)d_in[10];
    const float* alpha             = (const float*)d_in[11];
    const float* w_his1            = (const float*)d_in[12];
    const float* b_his1            = (const float*)d_in[13];
    const float* w_his2            = (const float*)d_in[14];
    const float* b_his2            = (const float*)d_in[15];
    const float* w_st              = (const float*)d_in[16];
    const float* b_st              = (const float*)d_in[17];
    const float* w_u               = (const float*)d_in[18];
    const float* b_u               = (const float*)d_in[19];
    float* out = (float*)d_out;
    float* ws  = (float*)d_ws;

    hipLaunchKernelGGL(k_pre, dim3(130), dim3(256), 0, stream,
                       user_embedding, station_embedding, raw_field_embed,
                       his_nodes, now_nodes, user_id, user_emb_table,
                       proj_w, proj_b, theta, alpha,
                       w_his1, b_his1, w_his2, b_his2,
                       w_st, b_st, w_u, b_u, ws);

    hipLaunchKernelGGL(k_main, dim3(NBLK), dim3(256), 0, stream,
                       station_emb_table, his_nodes, now_nodes, alpha, ws, out);
}